// Round 7
// baseline (282.728 us; speedup 1.0000x reference)
//
#include <hip/hip_runtime.h>

// Problem constants (B=1)
#define R_   384
#define P_   (R_ * R_)      // 147456 pairs
#define NT_  4              // templates
#define CIN  128            // z channels
#define CKV  64             // t channels
#define NH   4              // heads
#define HC   256            // NH * 64

#define TP   64             // pairs per block
#define LDA  280            // A/U row stride (bf16): 560B rows, 16B-aligned

typedef __attribute__((ext_vector_type(8))) short bf16x8;
typedef __attribute__((ext_vector_type(4))) float f32x4;
typedef __attribute__((ext_vector_type(4))) uint  u32x4;

// round-to-nearest-even f32 -> bf16 (bit-level)
__device__ __forceinline__ ushort f2bf_s(float f) {
    uint32_t u = __float_as_uint(f);
    u += 0x7FFFu + ((u >> 16) & 1u);
    return (ushort)(u >> 16);
}
__device__ __forceinline__ uint packbf2(float lo, float hi) {
    return (uint)f2bf_s(lo) | ((uint)f2bf_s(hi) << 16);
}
__device__ __forceinline__ float bflo(uint t) { return __uint_as_float(t << 16); }
__device__ __forceinline__ float bfhi(uint t) { return __uint_as_float(t & 0xffff0000u); }

union BF8 { bf16x8 v; uint u[4]; };

// ---------------------------------------------------------------------------
// Precompute Mt[n][ci] = C^-0.5 * sum_c Wq[ci][h*64+c] * Wk[j][h*64+c]   (n = h*64+j)
//            Gt[co][n] =         sum_c Wv[j][h*64+c] * Wo[h*64+c][co]
// ---------------------------------------------------------------------------
__global__ __launch_bounds__(256) void precompute_mg(
        const float* __restrict__ Wq, const float* __restrict__ Wk,
        const float* __restrict__ Wv, const float* __restrict__ Wo,
        ushort* __restrict__ Mt, ushort* __restrict__ Gt) {
    int tid = blockIdx.x * blockDim.x + threadIdx.x;
    if (tid < HC * CIN) {
        int n = tid >> 7, ci = tid & 127;
        int h = n >> 6, j = n & 63;
        float acc = 0.f;
        for (int c = 0; c < 64; ++c)
            acc += Wq[ci * HC + h * 64 + c] * Wk[j * HC + h * 64 + c];
        Mt[n * CIN + ci] = f2bf_s(acc * 0.125f);   // C^-0.5 = 1/8
    } else {
        int t = tid - HC * CIN;
        int co = t >> 8, n = t & 255;
        int h = n >> 6, j = n & 63;
        float acc = 0.f;
        for (int c = 0; c < 64; ++c)
            acc += Wv[j * HC + h * 64 + c] * Wo[(h * 64 + c) * CIN + co];
        Gt[co * HC + n] = f2bf_s(acc);
    }
}

// ---------------------------------------------------------------------------
// Fused kernel, one 64-pair tile per block, 2 barriers, LDS = sA only.
//   GEMM1 (Z frags from global, swapped mfma -> A^T tiles) ; packed spill ;
//   [barrier] middle (T fp32 from global, lane=(head,pair)) ; U -> sA ;
//   [barrier] GEMM2 (swapped) ; float4 stores.
// ---------------------------------------------------------------------------
__global__ __launch_bounds__(256, 3) void tpa_fused(
        const float* __restrict__ z2d, const float* __restrict__ t2d,
        const ushort* __restrict__ Mt, const ushort* __restrict__ Gt,
        const float* __restrict__ bo, float* __restrict__ out) {

    __shared__ ushort sA[TP * LDA];      // A (bf16) then U (bf16): 35.84 KB

    const int tid  = threadIdx.x;
    const int lane = tid & 63;
    const int wv   = tid >> 6;           // wave == head (GEMM1/GEMM2 col owner)
    const int lr   = lane & 15;
    const int g    = lane >> 4;          // 0..3
    const int g8   = g << 3;
    const int pg0  = blockIdx.x * TP;

    // ---- B1 fragments (GEMM1), L2-resident ------------------------------
    bf16x8 B1[4][4];   // [kt][nt]
    #pragma unroll
    for (int kt = 0; kt < 4; ++kt)
        #pragma unroll
        for (int nt = 0; nt < 4; ++nt)
            B1[kt][nt] = *(const bf16x8*)(Mt + (wv * 64 + nt * 16 + lr) * CIN + kt * 32 + g8);

    // ---- GEMM1 (swapped): acc1[nt][mt] = A^T tile ------------------------
    //      D[row=n-in-16][col=p-in-16]; n = wv*64+nt*16+g*4+r, p = mt*16+lr
    f32x4 acc1[4][4];
    #pragma unroll
    for (int nt = 0; nt < 4; ++nt)
        #pragma unroll
        for (int mt = 0; mt < 4; ++mt)
            acc1[nt][mt] = (f32x4){0.f, 0.f, 0.f, 0.f};

    #pragma unroll
    for (int kt = 0; kt < 4; ++kt) {
        bf16x8 zf[4];
        #pragma unroll
        for (int mt = 0; mt < 4; ++mt) {
            const float* zp = z2d + (size_t)(pg0 + mt * 16 + lr) * CIN + kt * 32 + g8;
            float4 z0 = *(const float4*)zp;
            float4 z1 = *(const float4*)(zp + 4);
            BF8 zb;
            zb.u[0] = packbf2(z0.x, z0.y); zb.u[1] = packbf2(z0.z, z0.w);
            zb.u[2] = packbf2(z1.x, z1.y); zb.u[3] = packbf2(z1.z, z1.w);
            zf[mt] = zb.v;
        }
        #pragma unroll
        for (int nt = 0; nt < 4; ++nt)
            #pragma unroll
            for (int mt = 0; mt < 4; ++mt)
                acc1[nt][mt] = __builtin_amdgcn_mfma_f32_16x16x32_bf16(
                    B1[kt][nt], zf[mt], acc1[nt][mt], 0, 0, 0);
    }

    // ---- spill A^T -> sA[p][n], packed b64 (4 consecutive n per write) ---
    #pragma unroll
    for (int nt = 0; nt < 4; ++nt) {
        int n0 = wv * 64 + nt * 16 + g * 4;
        #pragma unroll
        for (int mt = 0; mt < 4; ++mt) {
            int p = mt * 16 + lr;
            uint2 w;
            w.x = packbf2(acc1[nt][mt][0], acc1[nt][mt][1]);
            w.y = packbf2(acc1[nt][mt][2], acc1[nt][mt][3]);
            *(uint2*)&sA[p * LDA + n0] = w;
        }
    }

    // ---- B2 fragments + bias (issued here; consumed after middle) --------
    bf16x8 B2[8][2];   // [kt][nt]
    #pragma unroll
    for (int kt = 0; kt < 8; ++kt)
        #pragma unroll
        for (int nt = 0; nt < 2; ++nt)
            B2[kt][nt] = *(const bf16x8*)(Gt + (wv * 32 + nt * 16 + lr) * HC + kt * 32 + g8);
    float4 b4[2];
    #pragma unroll
    for (int nt = 0; nt < 2; ++nt)
        b4[nt] = *(const float4*)(bo + wv * 32 + nt * 16 + g * 4);

    __syncthreads();   // (1) A visible to all waves

    // ---- middle: lane = (head h = g, pair pp = lr); p = wv*16 + pp -------
    {
        const int h = g;
        const int p = wv * 16 + lr;
        const ushort* arow = &sA[p * LDA + h * 64];

        u32x4 a4[8];                     // 64 bf16 A-channels
        #pragma unroll
        for (int q = 0; q < 8; ++q) a4[q] = *(const u32x4*)&arow[q * 8];

        const float* tk0 = t2d + ((size_t)0 * P_ + pg0 + p) * CKV;
        const float* tk1 = t2d + ((size_t)1 * P_ + pg0 + p) * CKV;
        const float* tk2 = t2d + ((size_t)2 * P_ + pg0 + p) * CKV;
        const float* tk3 = t2d + ((size_t)3 * P_ + pg0 + p) * CKV;

        float lg0 = 0.f, lg1 = 0.f, lg2 = 0.f, lg3 = 0.f;
        #pragma unroll
        for (int q4 = 0; q4 < 16; ++q4) {
            float4 t0 = *(const float4*)(tk0 + q4 * 4);
            float4 t1 = *(const float4*)(tk1 + q4 * 4);
            float4 t2 = *(const float4*)(tk2 + q4 * 4);
            float4 t3 = *(const float4*)(tk3 + q4 * 4);
            uint ua = a4[q4 >> 1][(q4 & 1) * 2 + 0];   // ch q4*4 + 0,1
            uint ub = a4[q4 >> 1][(q4 & 1) * 2 + 1];   // ch q4*4 + 2,3
            float a0 = bflo(ua), a1 = bfhi(ua), a2 = bflo(ub), a3 = bfhi(ub);
            lg0 = fmaf(a0, t0.x, lg0); lg0 = fmaf(a1, t0.y, lg0);
            lg0 = fmaf(a2, t0.z, lg0); lg0 = fmaf(a3, t0.w, lg0);
            lg1 = fmaf(a0, t1.x, lg1); lg1 = fmaf(a1, t1.y, lg1);
            lg1 = fmaf(a2, t1.z, lg1); lg1 = fmaf(a3, t1.w, lg1);
            lg2 = fmaf(a0, t2.x, lg2); lg2 = fmaf(a1, t2.y, lg2);
            lg2 = fmaf(a2, t2.z, lg2); lg2 = fmaf(a3, t2.w, lg2);
            lg3 = fmaf(a0, t3.x, lg3); lg3 = fmaf(a1, t3.y, lg3);
            lg3 = fmaf(a2, t3.z, lg3); lg3 = fmaf(a3, t3.w, lg3);
        }
        float mx = fmaxf(fmaxf(lg0, lg1), fmaxf(lg2, lg3));
        float w0 = __expf(lg0 - mx), w1 = __expf(lg1 - mx);
        float w2 = __expf(lg2 - mx), w3 = __expf(lg3 - mx);
        float inv = 1.f / (w0 + w1 + w2 + w3);
        w0 *= inv; w1 *= inv; w2 *= inv; w3 *= inv;

        // U = sum_k w_k * T  (T re-read, L1-hot), packed bf16 -> sA
        ushort* urow = &sA[p * LDA + h * 64];
        #pragma unroll
        for (int q8 = 0; q8 < 8; ++q8) {
            float4 t0a = *(const float4*)(tk0 + q8 * 8), t0b = *(const float4*)(tk0 + q8 * 8 + 4);
            float4 t1a = *(const float4*)(tk1 + q8 * 8), t1b = *(const float4*)(tk1 + q8 * 8 + 4);
            float4 t2a = *(const float4*)(tk2 + q8 * 8), t2b = *(const float4*)(tk2 + q8 * 8 + 4);
            float4 t3a = *(const float4*)(tk3 + q8 * 8), t3b = *(const float4*)(tk3 + q8 * 8 + 4);
            float u0 = w0*t0a.x + w1*t1a.x + w2*t2a.x + w3*t3a.x;
            float u1 = w0*t0a.y + w1*t1a.y + w2*t2a.y + w3*t3a.y;
            float u2 = w0*t0a.z + w1*t1a.z + w2*t2a.z + w3*t3a.z;
            float u3 = w0*t0a.w + w1*t1a.w + w2*t2a.w + w3*t3a.w;
            float u4 = w0*t0b.x + w1*t1b.x + w2*t2b.x + w3*t3b.x;
            float u5 = w0*t0b.y + w1*t1b.y + w2*t2b.y + w3*t3b.y;
            float u6 = w0*t0b.z + w1*t1b.z + w2*t2b.z + w3*t3b.z;
            float u7 = w0*t0b.w + w1*t1b.w + w2*t2b.w + w3*t3b.w;
            u32x4 o;
            o[0] = packbf2(u0, u1); o[1] = packbf2(u2, u3);
            o[2] = packbf2(u4, u5); o[3] = packbf2(u6, u7);
            *(u32x4*)&urow[q8 * 8] = o;
        }
    }
    __syncthreads();   // (2) U visible to all waves

    // ---- GEMM2 (swapped): acc2[nt][mt] = OUT^T tile -----------------------
    //      D[row=co-in-16][col=p-in-16]; co = wv*32+nt*16+g*4+r, p = mt*16+lr
    f32x4 acc2[2][4];
    #pragma unroll
    for (int nt = 0; nt < 2; ++nt)
        #pragma unroll
        for (int mt = 0; mt < 4; ++mt)
            acc2[nt][mt] = (f32x4){0.f, 0.f, 0.f, 0.f};

    #pragma unroll
    for (int kt = 0; kt < 8; ++kt) {
        bf16x8 uf[4];
        #pragma unroll
        for (int mt = 0; mt < 4; ++mt)
            uf[mt] = *(const bf16x8*)&sA[(mt * 16 + lr) * LDA + kt * 32 + g8];
        #pragma unroll
        for (int nt = 0; nt < 2; ++nt)
            #pragma unroll
            for (int mt = 0; mt < 4; ++mt)
                acc2[nt][mt] = __builtin_amdgcn_mfma_f32_16x16x32_bf16(
                    B2[kt][nt], uf[mt], acc2[nt][mt], 0, 0, 0);
    }

    // ---- epilogue: bias + contiguous float4 stores ------------------------
    #pragma unroll
    for (int nt = 0; nt < 2; ++nt) {
        int co0 = wv * 32 + nt * 16 + g * 4;
        #pragma unroll
        for (int mt = 0; mt < 4; ++mt) {
            int p = mt * 16 + lr;
            float4 o;
            o.x = acc2[nt][mt][0] + b4[nt].x;
            o.y = acc2[nt][mt][1] + b4[nt].y;
            o.z = acc2[nt][mt][2] + b4[nt].z;
            o.w = acc2[nt][mt][3] + b4[nt].w;
            *(float4*)(out + (size_t)(pg0 + p) * CIN + co0) = o;
        }
    }
}

extern "C" void kernel_launch(void* const* d_in, const int* in_sizes, int n_in,
                              void* d_out, int out_size, void* d_ws, size_t ws_size,
                              hipStream_t stream) {
    const float* z2d = (const float*)d_in[0];
    const float* t2d = (const float*)d_in[1];
    const float* Wq  = (const float*)d_in[2];
    const float* Wk  = (const float*)d_in[3];
    const float* Wv  = (const float*)d_in[4];
    const float* Wo  = (const float*)d_in[5];
    const float* bo  = (const float*)d_in[6];

    ushort* Mt = (ushort*)d_ws;            // 256x128 bf16
    ushort* Gt = Mt + HC * CIN;            // 128x256 bf16

    precompute_mg<<<(2 * HC * CIN) / 256, 256, 0, stream>>>(Wq, Wk, Wv, Wo, Mt, Gt);
    tpa_fused<<<P_ / TP, 256, 0, stream>>>(z2d, t2d, Mt, Gt, bo, (float*)d_out);
}

// Round 8
// 88.993 us; speedup vs baseline: 3.1770x; 3.1770x over previous
//
#include <hip/hip_runtime.h>

// Problem constants (B=1)
#define R_   384
#define P_   (R_ * R_)      // 147456 pairs
#define NT_  4              // templates
#define CIN  128            // z channels
#define CKV  64             // t channels
#define NH   4              // heads
#define HC   256            // NH * 64

// Tiling
#define TP   64             // pairs per block
#define LDZ  136            // Z row stride (bf16) inside s0 during staging/GEMM1
#define LDA  280            // T/A row stride (bf16): 560B rows, 16B-aligned

typedef __attribute__((ext_vector_type(8))) short bf16x8;
typedef __attribute__((ext_vector_type(4))) float f32x4;
typedef __attribute__((ext_vector_type(4))) uint  u32x4;
typedef __attribute__((ext_vector_type(2))) __bf16 bfv2;

#if defined(__has_builtin)
#if __has_builtin(__builtin_amdgcn_fdot2_f32_bf16)
#define HAS_DOT2BF 1
#endif
#endif

// round-to-nearest-even f32 -> bf16 (bit-level, no HIP class types)
__device__ __forceinline__ ushort f2bf_s(float f) {
    uint32_t u = __float_as_uint(f);
    u += 0x7FFFu + ((u >> 16) & 1u);
    return (ushort)(u >> 16);
}
__device__ __forceinline__ uint packbf2(float lo, float hi) {
    return (uint)f2bf_s(lo) | ((uint)f2bf_s(hi) << 16);
}
__device__ __forceinline__ uint2 pack4(const float4 v) {
    uint2 r; r.x = packbf2(v.x, v.y); r.y = packbf2(v.z, v.w); return r;
}
__device__ __forceinline__ float bflo(uint t) { return __uint_as_float(t << 16); }
__device__ __forceinline__ float bfhi(uint t) { return __uint_as_float(t & 0xffff0000u); }

__device__ __forceinline__ float dot2bf(uint a, uint b, float acc) {
#ifdef HAS_DOT2BF
    union { uint u; bfv2 v; } ua, ub;
    ua.u = a; ub.u = b;
    return __builtin_amdgcn_fdot2_f32_bf16(ua.v, ub.v, acc, false);
#else
    float r = fmaf(bflo(a), bflo(b), acc);
    return fmaf(bfhi(a), bfhi(b), r);
#endif
}

// ---------------------------------------------------------------------------
// Precompute Mt[n][ci] = C^-0.5 * sum_c Wq[ci][h*64+c] * Wk[j][h*64+c]   (n = h*64+j)
//            Gt[co][n] =         sum_c Wv[j][h*64+c] * Wo[h*64+c][co]
// ---------------------------------------------------------------------------
__global__ __launch_bounds__(256) void precompute_mg(
        const float* __restrict__ Wq, const float* __restrict__ Wk,
        const float* __restrict__ Wv, const float* __restrict__ Wo,
        ushort* __restrict__ Mt, ushort* __restrict__ Gt) {
    int tid = blockIdx.x * blockDim.x + threadIdx.x;
    if (tid < HC * CIN) {
        int n = tid >> 7, ci = tid & 127;
        int h = n >> 6, j = n & 63;
        float acc = 0.f;
        for (int c = 0; c < 64; ++c)
            acc += Wq[ci * HC + h * 64 + c] * Wk[j * HC + h * 64 + c];
        Mt[n * CIN + ci] = f2bf_s(acc * 0.125f);   // C^-0.5 = 1/8
    } else {
        int t = tid - HC * CIN;
        int co = t >> 8, n = t & 255;
        int h = n >> 6, j = n & 63;
        float acc = 0.f;
        for (int c = 0; c < 64; ++c)
            acc += Wv[j * HC + h * 64 + c] * Wo[(h * 64 + c) * CIN + co];
        Gt[co * HC + n] = f2bf_s(acc);
    }
}

// ---------------------------------------------------------------------------
// Fused kernel, one 64-pair tile per block (r6 structure + T-overlap):
//   issue Z loads, issue T loads (stay in flight), stage Z -> LDS,
//   [lgkmcnt(0) + raw s_barrier]  <- T loads NOT drained here
//   GEMM1 (B1 regs, Z from LDS)  ||  T cvt+ds_write (counted vmcnt)
//   [syncthreads]  B2/bias loads ; spill A ; [wave-local fence] middle ;
//   [syncthreads]  GEMM2 ; bias ; store.
// ---------------------------------------------------------------------------
__global__ __launch_bounds__(256, 2) void tpa_fused(
        const float* __restrict__ z2d, const float* __restrict__ t2d,
        const ushort* __restrict__ Mt, const ushort* __restrict__ Gt,
        const float* __restrict__ bo, float* __restrict__ out) {

    __shared__ ushort s0[TP * LDA];   // Z (stride LDZ) during GEMM1, then A/U (stride LDA)
    __shared__ ushort sT[TP * LDA];   // T tile: sT[p*LDA + k*64 + c]

    const int tid  = threadIdx.x;
    const int lane = tid & 63;
    const int wv   = tid >> 6;           // wave == head
    const int lr   = lane & 15;
    const int lk   = (lane >> 4) << 3;
    const int pg0  = blockIdx.x * TP;

    // ---- B1 fragments (L2-resident, needed first) ------------------------
    bf16x8 B1[4][4];   // [kt][nt], wave wv -> cols [wv*64, +64)
    #pragma unroll
    for (int kt = 0; kt < 4; ++kt)
        #pragma unroll
        for (int nt = 0; nt < 4; ++nt)
            B1[kt][nt] = *(const bf16x8*)(Mt + (wv * 64 + nt * 16 + lr) * CIN + kt * 32 + lk);

    // ---- issue Z loads (8 x float4) --------------------------------------
    float4 zv[8];
    #pragma unroll
    for (int i = 0; i < 8; ++i) {
        int idx = (i * 256 + tid) * 4, p = idx >> 7, c = idx & 127;
        zv[i] = *(const float4*)(z2d + (size_t)(pg0 + p) * CIN + c);
    }
    // ---- issue T loads (16 x float4) — these stay in flight past bar1 ----
    float4 tv[16];
    #pragma unroll
    for (int k = 0; k < NT_; ++k) {
        const float* src = t2d + ((size_t)k * P_ + pg0) * CKV;
        #pragma unroll
        for (int i = 0; i < 4; ++i) {
            int idx = (i * 256 + tid) * 4, p = idx >> 6, c = idx & 63;
            tv[k * 4 + i] = *(const float4*)(src + p * 64 + c);
        }
    }

    // ---- stage Z -> LDS bf16 ---------------------------------------------
    #pragma unroll
    for (int i = 0; i < 8; ++i) {
        int idx = (i * 256 + tid) * 4, p = idx >> 7, c = idx & 127;
        *(uint2*)&s0[p * LDZ + c] = pack4(zv[i]);
    }

    // bar1: Z visible; do NOT drain vmcnt (T loads continue in flight)
    asm volatile("s_waitcnt lgkmcnt(0)" ::: "memory");
    __builtin_amdgcn_s_barrier();
    __builtin_amdgcn_sched_barrier(0);

    // ---- GEMM1: A[64][256] = Z[64][128] @ M' -----------------------------
    f32x4 acc1[4][4];
    #pragma unroll
    for (int mt = 0; mt < 4; ++mt)
        #pragma unroll
        for (int nt = 0; nt < 4; ++nt)
            acc1[mt][nt] = (f32x4){0.f, 0.f, 0.f, 0.f};
    #pragma unroll
    for (int kt = 0; kt < 4; ++kt) {
        bf16x8 af[4];
        #pragma unroll
        for (int mt = 0; mt < 4; ++mt)
            af[mt] = *(const bf16x8*)&s0[(mt * 16 + lr) * LDZ + kt * 32 + lk];
        #pragma unroll
        for (int mt = 0; mt < 4; ++mt)
            #pragma unroll
            for (int nt = 0; nt < 4; ++nt)
                acc1[mt][nt] = __builtin_amdgcn_mfma_f32_16x16x32_bf16(
                    af[mt], B1[kt][nt], acc1[mt][nt], 0, 0, 0);
    }

    // ---- T cvt + ds_write (loads landed during GEMM1) --------------------
    #pragma unroll
    for (int k = 0; k < NT_; ++k)
        #pragma unroll
        for (int i = 0; i < 4; ++i) {
            int idx = (i * 256 + tid) * 4, p = idx >> 6, c = idx & 63;
            *(uint2*)&sT[p * LDA + k * 64 + c] = pack4(tv[k * 4 + i]);
        }

    __syncthreads();   // bar2: Z-reads done (s0 reusable), sT visible

    // ---- B2 + bias loads: L2 latency hides under spill + middle ----------
    bf16x8 B2[8][2];   // [kt][nt], wave wv -> cols [wv*32, +32)
    #pragma unroll
    for (int kt = 0; kt < 8; ++kt)
        #pragma unroll
        for (int nt = 0; nt < 2; ++nt)
            B2[kt][nt] = *(const bf16x8*)(Gt + (wv * 32 + nt * 16 + lr) * HC + kt * 32 + lk);
    const float bias0 = bo[wv * 32 + lr];
    const float bias1 = bo[wv * 32 + 16 + lr];

    // ---- spill A (wave-local cols; C/D: col=lane&15, row=(lane>>4)*4+r) --
    #pragma unroll
    for (int mt = 0; mt < 4; ++mt) {
        int row = mt * 16 + ((lane >> 4) << 2);
        #pragma unroll
        for (int nt = 0; nt < 4; ++nt) {
            int n = wv * 64 + nt * 16 + lr;
            #pragma unroll
            for (int r = 0; r < 4; ++r)
                s0[(row + r) * LDA + n] = f2bf_s(acc1[mt][nt][r]);
        }
    }
    // same-wave cross-lane LDS RAW: drain DS pipe, pin order (rule #18)
    asm volatile("s_waitcnt lgkmcnt(0)" ::: "memory");
    __builtin_amdgcn_sched_barrier(0);

    // ---- middle: thread (p=lane, h=wv): logits, softmax, U ---------------
    {
        ushort* arow = &s0[lane * LDA + wv * 64];
        const ushort* trow = &sT[lane * LDA];

        u32x4 a4[8];
        #pragma unroll
        for (int q = 0; q < 8; ++q) a4[q] = *(const u32x4*)&arow[q * 8];

        float lg[4];
        #pragma unroll
        for (int k = 0; k < 4; ++k) {
            float s = 0.f;
            #pragma unroll
            for (int q = 0; q < 8; ++q) {
                u32x4 tq = *(const u32x4*)&trow[k * 64 + q * 8];
                #pragma unroll
                for (int e = 0; e < 4; ++e)
                    s = dot2bf(a4[q][e], tq[e], s);
            }
            lg[k] = s;
        }
        float mx = fmaxf(fmaxf(lg[0], lg[1]), fmaxf(lg[2], lg[3]));
        float w0 = __expf(lg[0] - mx), w1 = __expf(lg[1] - mx);
        float w2 = __expf(lg[2] - mx), w3 = __expf(lg[3] - mx);
        float inv = 1.f / (w0 + w1 + w2 + w3);
        w0 *= inv; w1 *= inv; w2 *= inv; w3 *= inv;

        #pragma unroll
        for (int q = 0; q < 8; ++q) {
            u32x4 t0 = *(const u32x4*)&trow[q * 8];
            u32x4 t1 = *(const u32x4*)&trow[64 + q * 8];
            u32x4 t2 = *(const u32x4*)&trow[128 + q * 8];
            u32x4 t3 = *(const u32x4*)&trow[192 + q * 8];
            u32x4 o;
            #pragma unroll
            for (int e = 0; e < 4; ++e) {
                float lo = w0 * bflo(t0[e]) + w1 * bflo(t1[e]) + w2 * bflo(t2[e]) + w3 * bflo(t3[e]);
                float hi = w0 * bfhi(t0[e]) + w1 * bfhi(t1[e]) + w2 * bfhi(t2[e]) + w3 * bfhi(t3[e]);
                o[e] = packbf2(lo, hi);
            }
            *(u32x4*)&arow[q * 8] = o;     // U overwrites own A slice (all 64 cols)
        }
    }
    __syncthreads();   // bar3: U visible to all waves

    // ---- GEMM2: OUT[64][128] = U[64][256] @ G ----------------------------
    f32x4 acc2[4][2];
    #pragma unroll
    for (int mt = 0; mt < 4; ++mt)
        #pragma unroll
        for (int nt = 0; nt < 2; ++nt)
            acc2[mt][nt] = (f32x4){0.f, 0.f, 0.f, 0.f};
    #pragma unroll
    for (int kt = 0; kt < 8; ++kt) {
        bf16x8 af[4];
        #pragma unroll
        for (int mt = 0; mt < 4; ++mt)
            af[mt] = *(const bf16x8*)&s0[(mt * 16 + lr) * LDA + kt * 32 + lk];
        #pragma unroll
        for (int mt = 0; mt < 4; ++mt)
            #pragma unroll
            for (int nt = 0; nt < 2; ++nt)
                acc2[mt][nt] = __builtin_amdgcn_mfma_f32_16x16x32_bf16(
                    af[mt], B2[kt][nt], acc2[mt][nt], 0, 0, 0);
    }

    // ---- epilogue: bias + fp32 store -------------------------------------
    #pragma unroll
    for (int nt = 0; nt < 2; ++nt) {
        int co = wv * 32 + nt * 16 + lr;
        float bias = nt ? bias1 : bias0;
        #pragma unroll
        for (int mt = 0; mt < 4; ++mt) {
            int row = mt * 16 + ((lane >> 4) << 2);
            #pragma unroll
            for (int r = 0; r < 4; ++r)
                out[(size_t)(pg0 + row + r) * CIN + co] = acc2[mt][nt][r] + bias;
        }
    }
}

extern "C" void kernel_launch(void* const* d_in, const int* in_sizes, int n_in,
                              void* d_out, int out_size, void* d_ws, size_t ws_size,
                              hipStream_t stream) {
    const float* z2d = (const float*)d_in[0];
    const float* t2d = (const float*)d_in[1];
    const float* Wq  = (const float*)d_in[2];
    const float* Wk  = (const float*)d_in[3];
    const float* Wv  = (const float*)d_in[4];
    const float* Wo  = (const float*)d_in[5];
    const float* bo  = (const float*)d_in[6];

    ushort* Mt = (ushort*)d_ws;            // 256x128 bf16
    ushort* Gt = Mt + HC * CIN;            // 128x256 bf16

    precompute_mg<<<(2 * HC * CIN) / 256, 256, 0, stream>>>(Wq, Wk, Wv, Wo, Mt, Gt);
    tpa_fused<<<P_ / TP, 256, 0, stream>>>(z2d, t2d, Mt, Gt, bo, (float*)d_out);
}